// Round 1
// baseline (563.790 us; speedup 1.0000x reference)
//
#include <hip/hip_runtime.h>
#include <hip/hip_bf16.h>

#define HDIM 128
#define RS 136  // LDS hidden row stride in bf16 elements (128 + 8 pad)

typedef __attribute__((ext_vector_type(8))) short short8;
typedef __attribute__((ext_vector_type(4))) float floatv4;

static __device__ __forceinline__ unsigned short f2bf(float f) {
  union { float f; unsigned u; } x; x.f = f;
  unsigned r = x.u + 0x7fffu + ((x.u >> 16) & 1u);  // RNE
  return (unsigned short)(r >> 16);
}
static __device__ __forceinline__ float blo(unsigned u) { return __uint_as_float(u << 16); }
static __device__ __forceinline__ float bhi(unsigned u) { return __uint_as_float(u & 0xffff0000u); }

// Raw workgroup barrier WITHOUT the vmcnt(0) drain __syncthreads() emits.
// Keeps cross-session prefetch global loads in flight across phase boundaries.
// Pattern verified in the 8-phase GEMM template (m201): lgkmcnt(0) makes this
// thread's LDS writes visible, s_barrier syncs, trailing compiler fence stops
// post-barrier LDS ops from hoisting above.
static __device__ __forceinline__ void sync_lds() {
  asm volatile("s_waitcnt lgkmcnt(0)" ::: "memory");
  __builtin_amdgcn_s_barrier();
  asm volatile("" ::: "memory");
}

// Merged prep: block 0 scans seq_len -> offs; blocks 1..128 convert weights to bf16.
__global__ void prep_kernel(const int* __restrict__ seq, int* __restrict__ offs, int B,
                            const float* __restrict__ W1, const float* __restrict__ W2,
                            const float* __restrict__ W3,
                            unsigned short* __restrict__ w1b, unsigned short* __restrict__ w2b,
                            unsigned short* __restrict__ w3b) {
  if (blockIdx.x == 0) {
    __shared__ int part[256];
    int tid = threadIdx.x;
    int chunk = (B + 255) >> 8;
    int beg = tid * chunk, end = min(beg + chunk, B);
    int s = 0;
    for (int i = beg; i < end; ++i) s += seq[i];
    part[tid] = s;
    __syncthreads();
    for (int d = 1; d < 256; d <<= 1) {
      int v = (tid >= d) ? part[tid - d] : 0;
      __syncthreads();
      part[tid] += v;
      __syncthreads();
    }
    int run = (tid == 0) ? 0 : part[tid - 1];
    for (int i = beg; i < end; ++i) { offs[i] = run; run += seq[i]; }
  } else {
    int i = (blockIdx.x - 1) * 256 + threadIdx.x;
    if (i < 16384) { w1b[i] = f2bf(W1[i]); w2b[i] = f2bf(W2[i]); }
    if (i < 32768) { w3b[i] = f2bf(W3[i]); }
  }
}

// Grid-strided: each block processes B/gridDim sessions, prefetching session
// i+1's token rows into registers while computing session i.
// __launch_bounds__(256,3): cap ~170 VGPRs, spill-free headroom for the 64
// prefetch regs + 32 resident W2-frag regs. 3 blocks/CU is enough — latency
// hiding comes from the prefetch, not TLP.
__global__ __launch_bounds__(256, 3) void session_kernel(
    const float* __restrict__ intra, const float* __restrict__ inter,
    const unsigned short* __restrict__ w1b, const float* __restrict__ b1,
    const unsigned short* __restrict__ w2b, const float* __restrict__ b2,
    const float* __restrict__ qw, const float* __restrict__ qb,
    const unsigned short* __restrict__ w3b, const float* __restrict__ b3,
    const int* __restrict__ seq, const int* __restrict__ offs,
    float* __restrict__ out, int B) {
  __shared__ unsigned short hbf[64 * RS];   // bf16 hidden tile, zero-padded (17408 B)
  __shared__ unsigned short vnb[HDIM];      // bf16 v_n
  __shared__ unsigned short sgb[HDIM];      // bf16 s_g
  __shared__ float alphaAcc[64];
  __shared__ float sgpart[4][HDIM];

  const int tid = threadIdx.x;
  const int lane = tid & 63, wid = tid >> 6;
  const int quad = lane >> 4, lcol = lane & 15;
  const int nbase = wid << 5;
  const int n0 = nbase + lcol, n1 = n0 + 16;  // this lane's two output columns
  const int G = gridDim.x;

  // Loop-invariant per-lane scalars.
  const float qb0 = qb[0];
  const float bb0 = b1[n0] + b2[n0], bb1 = b1[n1] + b2[n1];
  const float q0 = qw[n0], q1 = qw[n1];
  const float b30 = b3[n0], b31 = b3[n1];

  // W2 B-fragments (B[k][n] = W2[n][k]): lane-dependent only -> load ONCE,
  // resident across all sessions. Keeps the main loop free of global loads
  // issued after the prefetch (vmcnt FIFO: waiting on a younger load would
  // drain the prefetch).
  short8 w2f[2][4];
  #pragma unroll
  for (int nt = 0; nt < 2; ++nt) {
    int nn = nbase + (nt << 4) + lcol;
    #pragma unroll
    for (int kt = 0; kt < 4; ++kt)
      w2f[nt][kt] = *(const short8*)(w2b + nn * HDIM + (kt << 5) + (quad << 3));
  }

  // ---- Prologue: issue first session's loads ----
  float4 ra[8], rb[8];
  int n_cur;
  {
    int s0 = blockIdx.x;
    n_cur = seq[s0]; if (n_cur > 64) n_cur = 64;  // dataset: L == 50
    int st0 = offs[s0];
    const float4* pa = (const float4*)(intra + (size_t)st0 * HDIM);
    const float4* pb = (const float4*)(inter + (size_t)st0 * HDIM);
    #pragma unroll
    for (int it = 0; it < 8; ++it) {
      int idx = (it << 8) + tid, t = idx >> 5;
      float4 z; z.x = 0.f; z.y = 0.f; z.z = 0.f; z.w = 0.f;
      float4 va = z, vb = z;
      if (t < n_cur) { va = pa[idx]; vb = pb[idx]; }
      ra[it] = va; rb[it] = vb;
    }
  }

  for (int s = blockIdx.x; s < B; s += G) {
    const int sn = s + G;
    int n_nxt = 0, st_nxt = 0;
    if (sn < B) { n_nxt = seq[sn]; if (n_nxt > 64) n_nxt = 64; st_nxt = offs[sn]; }

    // ---- consume prefetched regs -> bf16 LDS tile; v_n row; alpha init ----
    const int lastrow = (n_cur > 0) ? (n_cur - 1) : 0;
    #pragma unroll
    for (int it = 0; it < 8; ++it) {
      int idx = (it << 8) + tid;       // float4 index; linear over 64x128 tile
      int t = idx >> 5, j4 = idx & 31;
      float4 a = ra[it], c = rb[it];   // rows >= n were zero-filled at issue
      union { __hip_bfloat162 b; unsigned u; } p01, p23;
      p01.b = __float22bfloat162_rn(make_float2(fmaxf(a.x, c.x), fmaxf(a.y, c.y)));
      p23.b = __float22bfloat162_rn(make_float2(fmaxf(a.z, c.z), fmaxf(a.w, c.w)));
      uint2 st; st.x = p01.u; st.y = p23.u;
      *(uint2*)&hbf[t * RS + (j4 << 2)] = st;
      if (t == lastrow) *(uint2*)&vnb[j4 << 2] = st;   // v_n = last valid row
    }
    if (tid < 64) alphaAcc[tid] = qb0;
    sync_lds();  // B1: tile + v_n visible

    // ---- W1 pre-pass: c[n] = W1 @ v_n + b1 + b2 via broadcast-A MFMA ----
    // Issued & consumed BEFORE the prefetch so its vmcnt wait is cheap.
    float c0, c1;
    {
      floatv4 p0 = {0.f, 0.f, 0.f, 0.f}, p1 = {0.f, 0.f, 0.f, 0.f};
      #pragma unroll
      for (int kt = 0; kt < 4; ++kt) {
        short8 af = *(const short8*)&vnb[(kt << 5) + (quad << 3)];
        short8 bf0 = *(const short8*)(w1b + n0 * HDIM + (kt << 5) + (quad << 3));
        short8 bf1 = *(const short8*)(w1b + n1 * HDIM + (kt << 5) + (quad << 3));
        p0 = __builtin_amdgcn_mfma_f32_16x16x32_bf16(af, bf0, p0, 0, 0, 0);
        p1 = __builtin_amdgcn_mfma_f32_16x16x32_bf16(af, bf1, p1, 0, 0, 0);
      }
      c0 = p0[0] + bb0;
      c1 = p1[0] + bb1;
    }

    // ---- issue NEXT session's loads; they stream under all compute below ----
    if (sn < B) {
      const float4* pa = (const float4*)(intra + (size_t)st_nxt * HDIM);
      const float4* pb = (const float4*)(inter + (size_t)st_nxt * HDIM);
      #pragma unroll
      for (int it = 0; it < 8; ++it) {
        int idx = (it << 8) + tid, t = idx >> 5;
        float4 z; z.x = 0.f; z.y = 0.f; z.z = 0.f; z.w = 0.f;
        float4 va = z, vb = z;
        if (t < n_nxt) { va = pa[idx]; vb = pb[idx]; }
        ra[it] = va; rb[it] = vb;
      }
    }
    asm volatile("" ::: "memory");  // pin prefetch issue point

    // ---- main: D = hidden @ W2^T + c via MFMA; fused sigmoid + q-dot ----
    #pragma unroll
    for (int mt = 0; mt < 4; ++mt) {
      floatv4 a0 = {c0, c0, c0, c0}, a1 = {c1, c1, c1, c1};
      const unsigned short* arow = &hbf[((mt << 4) + lcol) * RS + (quad << 3)];
      #pragma unroll
      for (int kt = 0; kt < 4; ++kt) {
        short8 af = *(const short8*)(arow + (kt << 5));
        a0 = __builtin_amdgcn_mfma_f32_16x16x32_bf16(af, w2f[0][kt], a0, 0, 0, 0);
        a1 = __builtin_amdgcn_mfma_f32_16x16x32_bf16(af, w2f[1][kt], a1, 0, 0, 0);
      }
      // lane holds D[m = quad*4 + r][n0], D[m][n1]
      #pragma unroll
      for (int r = 0; r < 4; ++r) {
        float v = q0 * __builtin_amdgcn_rcpf(1.f + __expf(-a0[r]))
                + q1 * __builtin_amdgcn_rcpf(1.f + __expf(-a1[r]));
        v += __shfl_xor(v, 1, 64);
        v += __shfl_xor(v, 2, 64);
        v += __shfl_xor(v, 4, 64);
        v += __shfl_xor(v, 8, 64);
        if (lcol == 0) atomicAdd(&alphaAcc[(mt << 4) + (quad << 2) + r], v);
      }
    }
    sync_lds();  // B2: alphaAcc complete

    // ---- s_g: vectorized b128 reads, parallel over tokens ----
    {
      int jg = tid & 15, ts = tid >> 4;  // 16 col-groups x 16 token-slots
      float ac[8];
      #pragma unroll
      for (int e = 0; e < 8; ++e) ac[e] = 0.f;
      #pragma unroll
      for (int tt = 0; tt < 4; ++tt) {
        int t = (tt << 4) + ts;
        float al = alphaAcc[t];
        uint4 u = *(const uint4*)&hbf[t * RS + (jg << 3)];
        ac[0] += al * blo(u.x); ac[1] += al * bhi(u.x);
        ac[2] += al * blo(u.y); ac[3] += al * bhi(u.y);
        ac[4] += al * blo(u.z); ac[5] += al * bhi(u.z);
        ac[6] += al * blo(u.w); ac[7] += al * bhi(u.w);
      }
      #pragma unroll
      for (int e = 0; e < 8; ++e) {
        ac[e] += __shfl_xor(ac[e], 16, 64);
        ac[e] += __shfl_xor(ac[e], 32, 64);
      }
      if (quad == 0) {  // lanes 0..15 of each wave hold sums over its 4 token-slots
        float4 s0v; s0v.x = ac[0]; s0v.y = ac[1]; s0v.z = ac[2]; s0v.w = ac[3];
        float4 s1v; s1v.x = ac[4]; s1v.y = ac[5]; s1v.z = ac[6]; s1v.w = ac[7];
        *(float4*)&sgpart[wid][(jg << 3)] = s0v;
        *(float4*)&sgpart[wid][(jg << 3) + 4] = s1v;
      }
    }
    sync_lds();  // B3: sgpart complete
    if (tid < HDIM) {
      float sv = sgpart[0][tid] + sgpart[1][tid] + sgpart[2][tid] + sgpart[3][tid];
      sgb[tid] = f2bf(sv);
    }
    sync_lds();  // B4: sgb visible

    // ---- h_s = [v_n, s_g] @ W3^T + b3 via broadcast-A MFMA ----
    // w3b loads are issued after the prefetch; by now (main + s_g later) the
    // prefetch has mostly landed, so the implied vmcnt drain is cheap.
    {
      floatv4 o0 = {0.f, 0.f, 0.f, 0.f}, o1 = {0.f, 0.f, 0.f, 0.f};
      #pragma unroll
      for (int kt = 0; kt < 8; ++kt) {
        const unsigned short* src = (kt < 4) ? &vnb[kt << 5] : &sgb[(kt - 4) << 5];
        short8 af = *(const short8*)(src + (quad << 3));
        short8 bf0 = *(const short8*)(w3b + n0 * 256 + (kt << 5) + (quad << 3));
        short8 bf1 = *(const short8*)(w3b + n1 * 256 + (kt << 5) + (quad << 3));
        o0 = __builtin_amdgcn_mfma_f32_16x16x32_bf16(af, bf0, o0, 0, 0, 0);
        o1 = __builtin_amdgcn_mfma_f32_16x16x32_bf16(af, bf1, o1, 0, 0, 0);
      }
      if (quad == 0) {
        out[(size_t)s * HDIM + n0] = o0[0] + b30;
        out[(size_t)s * HDIM + n1] = o1[0] + b31;
      }
    }
    sync_lds();  // B5: protect hbf/vnb/sgb/alphaAcc before next consume

    n_cur = n_nxt;
  }
}

extern "C" void kernel_launch(void* const* d_in, const int* in_sizes, int n_in,
                              void* d_out, int out_size, void* d_ws, size_t ws_size,
                              hipStream_t stream) {
  const float* intra = (const float*)d_in[0];
  const float* inter = (const float*)d_in[1];
  const float* W1 = (const float*)d_in[2];
  const float* b1 = (const float*)d_in[3];
  const float* W2 = (const float*)d_in[4];
  const float* b2 = (const float*)d_in[5];
  const float* qw = (const float*)d_in[6];
  const float* qb = (const float*)d_in[7];
  const float* W3 = (const float*)d_in[8];
  const float* b3 = (const float*)d_in[9];
  const int* seq = (const int*)d_in[10];
  const int B = in_sizes[10];
  float* out = (float*)d_out;

  char* ws = (char*)d_ws;
  size_t o1 = (((size_t)B * 4) + 255) & ~(size_t)255;  // after offsets
  int* offs = (int*)ws;
  unsigned short* w1b = (unsigned short*)(ws + o1);            // 32 KB
  unsigned short* w2b = (unsigned short*)(ws + o1 + 32768);    // 32 KB
  unsigned short* w3b = (unsigned short*)(ws + o1 + 65536);    // 64 KB

  int nblk = B < 2048 ? B : 2048;  // grid-stride: ~4 sessions/block at B=8192

  hipLaunchKernelGGL(prep_kernel, dim3(129), dim3(256), 0, stream,
                     seq, offs, B, W1, W2, W3, w1b, w2b, w3b);
  hipLaunchKernelGGL(session_kernel, dim3(nblk), dim3(256), 0, stream,
                     intra, inter, w1b, b1, w2b, b2, qw, qb, w3b, b3, seq, offs, out, B);
}

// Round 2
// 532.577 us; speedup vs baseline: 1.0586x; 1.0586x over previous
//
#include <hip/hip_runtime.h>
#include <hip/hip_bf16.h>

#define HDIM 128
#define RS 136  // LDS hidden row stride in bf16 elements (128 + 8 pad)

typedef __attribute__((ext_vector_type(8))) short short8;
typedef __attribute__((ext_vector_type(4))) float floatv4;

static __device__ __forceinline__ unsigned short f2bf(float f) {
  union { float f; unsigned u; } x; x.f = f;
  unsigned r = x.u + 0x7fffu + ((x.u >> 16) & 1u);  // RNE
  return (unsigned short)(r >> 16);
}
static __device__ __forceinline__ float blo(unsigned u) { return __uint_as_float(u << 16); }
static __device__ __forceinline__ float bhi(unsigned u) { return __uint_as_float(u & 0xffff0000u); }

// ---- async global->LDS DMA (no VGPR round-trip; tracked by vmcnt) ----
// LDS dest is wave-uniform base + lane*size (hardware adds the lane term).
// Pointer casts go through integer to sidestep addrspace-cast restrictions;
// generic LDS addresses carry the offset in the low 32 bits.
static __device__ __forceinline__ void glds16(const void* g, const void* l) {
  __builtin_amdgcn_global_load_lds(
      (const __attribute__((address_space(1))) unsigned int*)(unsigned long long)g,
      (__attribute__((address_space(3))) unsigned int*)(unsigned long long)l, 16, 0, 0);
}
static __device__ __forceinline__ void glds4(const void* g, const void* l) {
  __builtin_amdgcn_global_load_lds(
      (const __attribute__((address_space(1))) unsigned int*)(unsigned long long)g,
      (__attribute__((address_space(3))) unsigned int*)(unsigned long long)l, 4, 0, 0);
}

// Raw barriers: __syncthreads() would drain vmcnt(0) and kill the in-flight DMA.
static __device__ __forceinline__ void sync_lds() {   // LDS-producer barrier
  asm volatile("s_waitcnt lgkmcnt(0)" ::: "memory");
  __builtin_amdgcn_s_barrier();
  asm volatile("" ::: "memory");
}
static __device__ __forceinline__ void sync_all() {   // DMA-drain barrier
  asm volatile("s_waitcnt vmcnt(0) lgkmcnt(0)" ::: "memory");
  __builtin_amdgcn_s_barrier();
  asm volatile("" ::: "memory");
}

// Issue DMA of one session's token rows (n rows x 512 B per stream), both
// streams, into contiguous LDS raw buffers. Row-pair (1 KB) granularity,
// interleaved across the 4 waves; odd tail row via 4 dword-sized issues.
static __device__ __forceinline__ void dma_session(
    const float* __restrict__ intra, const float* __restrict__ inter,
    int start, int n, float* rawA, float* rawB, int wid, int lane) {
  const char* ga = (const char*)(intra + (size_t)start * HDIM);
  const char* gb = (const char*)(inter + (size_t)start * HDIM);
  char* la = (char*)rawA;
  char* lb = (char*)rawB;
  int nfull = n >> 1;  // 1-KB chunks (2 rows each)
  for (int i = wid; i < nfull; i += 4) {
    int off = i << 10;
    glds16(ga + off + (lane << 4), la + off);
    glds16(gb + off + (lane << 4), lb + off);
  }
  if ((n & 1) && wid == 0) {        // tail row: 512 B = 2 x 256-B dword issues
    int off = (n - 1) << 9;
    glds4(ga + off + (lane << 2), la + off);
    glds4(ga + off + 256 + (lane << 2), la + off + 256);
    glds4(gb + off + (lane << 2), lb + off);
    glds4(gb + off + 256 + (lane << 2), lb + off + 256);
  }
}

// Merged prep: block 0 scans seq_len -> offs; blocks 1..128 convert weights to bf16.
__global__ void prep_kernel(const int* __restrict__ seq, int* __restrict__ offs, int B,
                            const float* __restrict__ W1, const float* __restrict__ W2,
                            const float* __restrict__ W3,
                            unsigned short* __restrict__ w1b, unsigned short* __restrict__ w2b,
                            unsigned short* __restrict__ w3b) {
  if (blockIdx.x == 0) {
    __shared__ int part[256];
    int tid = threadIdx.x;
    int chunk = (B + 255) >> 8;
    int beg = tid * chunk, end = min(beg + chunk, B);
    int s = 0;
    for (int i = beg; i < end; ++i) s += seq[i];
    part[tid] = s;
    __syncthreads();
    for (int d = 1; d < 256; d <<= 1) {
      int v = (tid >= d) ? part[tid - d] : 0;
      __syncthreads();
      part[tid] += v;
      __syncthreads();
    }
    int run = (tid == 0) ? 0 : part[tid - 1];
    for (int i = beg; i < end; ++i) { offs[i] = run; run += seq[i]; }
  } else {
    int i = (blockIdx.x - 1) * 256 + threadIdx.x;
    if (i < 16384) { w1b[i] = f2bf(W1[i]); w2b[i] = f2bf(W2[i]); }
    if (i < 32768) { w3b[i] = f2bf(W3[i]); }
  }
}

// 1 block/CU (LDS-limited), 4 waves. DMA double-buffers raw fp32 token tiles;
// ALL weight fragments live in registers (1 wave/SIMD -> up to 512 VGPR/wave),
// so the K-loop's only VMEM ops are the DMA issues: vmcnt(0) at the iteration
// top is an exact wait for the current session's staging.
__global__ __launch_bounds__(256, 1) void session_kernel(
    const float* __restrict__ intra, const float* __restrict__ inter,
    const unsigned short* __restrict__ w1b, const float* __restrict__ b1,
    const unsigned short* __restrict__ w2b, const float* __restrict__ b2,
    const float* __restrict__ qw, const float* __restrict__ qb,
    const unsigned short* __restrict__ w3b, const float* __restrict__ b3,
    const int* __restrict__ seq, const int* __restrict__ offs,
    float* __restrict__ out, int B) {
  __shared__ float rawA[2][64 * HDIM];      // 64 KB: intra fp32, double-buffered
  __shared__ float rawB[2][64 * HDIM];      // 64 KB: inter fp32, double-buffered
  __shared__ unsigned short hbf[64 * RS];   // bf16 hidden tile, zero-padded rows
  __shared__ unsigned short vnb[HDIM];      // bf16 v_n
  __shared__ unsigned short sgb[HDIM];      // bf16 s_g
  __shared__ float alphaAcc[64];
  __shared__ float sgpart[4][HDIM];

  const int tid = threadIdx.x;
  const int lane = tid & 63, wid = tid >> 6;
  const int quad = lane >> 4, lcol = lane & 15;
  const int nbase = wid << 5;
  const int n0 = nbase + lcol, n1 = n0 + 16;  // this lane's two output columns
  const int G = gridDim.x;

  // Loop-invariant scalars.
  const float qb0 = qb[0];
  const float bb0 = b1[n0] + b2[n0], bb1 = b1[n1] + b2[n1];
  const float q0 = qw[n0], q1 = qw[n1];
  const float b30 = b3[n0], b31 = b3[n1];

  // ALL weight fragments resident in registers across the whole session loop
  // (w1f 32 + w2f 32 + w3f 64 = 128 VGPRs). Keeps the loop free of non-DMA
  // VMEM loads -> vmcnt discipline stays exact, no per-session reload stalls.
  short8 w1f[2][4], w2f[2][4], w3f[2][8];
  #pragma unroll
  for (int kt = 0; kt < 4; ++kt) {
    w1f[0][kt] = *(const short8*)(w1b + n0 * HDIM + (kt << 5) + (quad << 3));
    w1f[1][kt] = *(const short8*)(w1b + n1 * HDIM + (kt << 5) + (quad << 3));
    w2f[0][kt] = *(const short8*)(w2b + n0 * HDIM + (kt << 5) + (quad << 3));
    w2f[1][kt] = *(const short8*)(w2b + n1 * HDIM + (kt << 5) + (quad << 3));
  }
  #pragma unroll
  for (int kt = 0; kt < 8; ++kt) {
    w3f[0][kt] = *(const short8*)(w3b + n0 * 256 + (kt << 5) + (quad << 3));
    w3f[1][kt] = *(const short8*)(w3b + n1 * 256 + (kt << 5) + (quad << 3));
  }

  // Prologue: issue first session's DMA into buffer 0.
  int n_cur;
  {
    int s0 = blockIdx.x;
    n_cur = seq[s0]; if (n_cur > 64) n_cur = 64;  // dataset: L == 50
    dma_session(intra, inter, offs[s0], n_cur, rawA[0], rawB[0], wid, lane);
  }
  int cur = 0;

  for (int s = blockIdx.x; s < B; s += G) {
    const int sn = s + G;
    int n_nxt = 0, st_nxt = 0;
    if (sn < B) {  // scalar loads overlap the vmcnt wait below
      n_nxt = seq[sn]; if (n_nxt > 64) n_nxt = 64;
      st_nxt = offs[sn];
    }

    // (1) current session's DMA complete (all waves drain their own issues)
    sync_all();

    // (2) immediately refill the pipe: issue NEXT session's DMA into the
    // other buffer (its last reader was the previous iteration's convert,
    // which is behind the barrier above). Streams under everything below.
    if (sn < B)
      dma_session(intra, inter, st_nxt, n_nxt, rawA[cur ^ 1], rawB[cur ^ 1], wid, lane);
    asm volatile("" ::: "memory");  // pin issue point

    // (3) convert raw fp32 -> bf16 hidden tile; extract v_n; init alphaAcc
    {
      const float4* a4 = (const float4*)rawA[cur];
      const float4* c4 = (const float4*)rawB[cur];
      const int lastrow = (n_cur > 0) ? (n_cur - 1) : 0;
      #pragma unroll
      for (int it = 0; it < 8; ++it) {
        int idx = (it << 8) + tid;       // float4 index; linear over 64x128 tile
        int t = idx >> 5, j4 = idx & 31;
        float4 r; r.x = 0.f; r.y = 0.f; r.z = 0.f; r.w = 0.f;
        if (t < n_cur) {
          float4 a = a4[idx], c = c4[idx];
          r.x = fmaxf(a.x, c.x); r.y = fmaxf(a.y, c.y);
          r.z = fmaxf(a.z, c.z); r.w = fmaxf(a.w, c.w);
        }
        union { __hip_bfloat162 b; unsigned u; } p01, p23;
        p01.b = __float22bfloat162_rn(make_float2(r.x, r.y));
        p23.b = __float22bfloat162_rn(make_float2(r.z, r.w));
        uint2 st; st.x = p01.u; st.y = p23.u;
        *(uint2*)&hbf[t * RS + (j4 << 2)] = st;
        if (t == lastrow) *(uint2*)&vnb[j4 << 2] = st;   // v_n = last valid row
      }
      if (tid < 64) alphaAcc[tid] = qb0;
    }
    sync_lds();  // B1: tile + v_n + alphaAcc init visible

    // (4) W1 pre-pass: c[n] = W1 @ v_n + b1 + b2 via broadcast-A MFMA
    float c0, c1;
    {
      floatv4 p0 = {0.f, 0.f, 0.f, 0.f}, p1 = {0.f, 0.f, 0.f, 0.f};
      #pragma unroll
      for (int kt = 0; kt < 4; ++kt) {
        short8 af = *(const short8*)&vnb[(kt << 5) + (quad << 3)];
        p0 = __builtin_amdgcn_mfma_f32_16x16x32_bf16(af, w1f[0][kt], p0, 0, 0, 0);
        p1 = __builtin_amdgcn_mfma_f32_16x16x32_bf16(af, w1f[1][kt], p1, 0, 0, 0);
      }
      c0 = p0[0] + bb0;
      c1 = p1[0] + bb1;
    }

    // (5) main: D = hidden @ W2^T + c via MFMA; fused sigmoid + q-dot
    #pragma unroll
    for (int mt = 0; mt < 4; ++mt) {
      floatv4 a0 = {c0, c0, c0, c0}, a1 = {c1, c1, c1, c1};
      const unsigned short* arow = &hbf[((mt << 4) + lcol) * RS + (quad << 3)];
      #pragma unroll
      for (int kt = 0; kt < 4; ++kt) {
        short8 af = *(const short8*)(arow + (kt << 5));
        a0 = __builtin_amdgcn_mfma_f32_16x16x32_bf16(af, w2f[0][kt], a0, 0, 0, 0);
        a1 = __builtin_amdgcn_mfma_f32_16x16x32_bf16(af, w2f[1][kt], a1, 0, 0, 0);
      }
      // lane holds D[m = quad*4 + r][n0], D[m][n1]
      #pragma unroll
      for (int r = 0; r < 4; ++r) {
        float v = q0 * __builtin_amdgcn_rcpf(1.f + __expf(-a0[r]))
                + q1 * __builtin_amdgcn_rcpf(1.f + __expf(-a1[r]));
        v += __shfl_xor(v, 1, 64);
        v += __shfl_xor(v, 2, 64);
        v += __shfl_xor(v, 4, 64);
        v += __shfl_xor(v, 8, 64);
        if (lcol == 0) atomicAdd(&alphaAcc[(mt << 4) + (quad << 2) + r], v);
      }
    }
    sync_lds();  // B2: alphaAcc complete

    // (6) s_g: vectorized b128 reads, parallel over tokens
    {
      int jg = tid & 15, ts = tid >> 4;  // 16 col-groups x 16 token-slots
      float ac[8];
      #pragma unroll
      for (int e = 0; e < 8; ++e) ac[e] = 0.f;
      #pragma unroll
      for (int tt = 0; tt < 4; ++tt) {
        int t = (tt << 4) + ts;
        float al = alphaAcc[t];
        uint4 u = *(const uint4*)&hbf[t * RS + (jg << 3)];
        ac[0] += al * blo(u.x); ac[1] += al * bhi(u.x);
        ac[2] += al * blo(u.y); ac[3] += al * bhi(u.y);
        ac[4] += al * blo(u.z); ac[5] += al * bhi(u.z);
        ac[6] += al * blo(u.w); ac[7] += al * bhi(u.w);
      }
      #pragma unroll
      for (int e = 0; e < 8; ++e) {
        ac[e] += __shfl_xor(ac[e], 16, 64);
        ac[e] += __shfl_xor(ac[e], 32, 64);
      }
      if (quad == 0) {  // lanes 0..15 of each wave hold sums over its 4 token-slots
        float4 s0v; s0v.x = ac[0]; s0v.y = ac[1]; s0v.z = ac[2]; s0v.w = ac[3];
        float4 s1v; s1v.x = ac[4]; s1v.y = ac[5]; s1v.z = ac[6]; s1v.w = ac[7];
        *(float4*)&sgpart[wid][(jg << 3)] = s0v;
        *(float4*)&sgpart[wid][(jg << 3) + 4] = s1v;
      }
    }
    sync_lds();  // B3: sgpart complete
    if (tid < HDIM) {
      float sv = sgpart[0][tid] + sgpart[1][tid] + sgpart[2][tid] + sgpart[3][tid];
      sgb[tid] = f2bf(sv);
    }
    sync_lds();  // B4: sgb visible

    // (7) h_s = [v_n, s_g] @ W3^T + b3 via broadcast-A MFMA (weights in regs)
    {
      floatv4 o0 = {0.f, 0.f, 0.f, 0.f}, o1 = {0.f, 0.f, 0.f, 0.f};
      #pragma unroll
      for (int kt = 0; kt < 8; ++kt) {
        const unsigned short* src = (kt < 4) ? &vnb[kt << 5] : &sgb[(kt - 4) << 5];
        short8 af = *(const short8*)(src + (quad << 3));
        o0 = __builtin_amdgcn_mfma_f32_16x16x32_bf16(af, w3f[0][kt], o0, 0, 0, 0);
        o1 = __builtin_amdgcn_mfma_f32_16x16x32_bf16(af, w3f[1][kt], o1, 0, 0, 0);
      }
      if (quad == 0) {
        out[(size_t)s * HDIM + n0] = o0[0] + b30;
        out[(size_t)s * HDIM + n1] = o1[0] + b31;
      }
    }

    cur ^= 1;
    n_cur = n_nxt;
  }
}

extern "C" void kernel_launch(void* const* d_in, const int* in_sizes, int n_in,
                              void* d_out, int out_size, void* d_ws, size_t ws_size,
                              hipStream_t stream) {
  const float* intra = (const float*)d_in[0];
  const float* inter = (const float*)d_in[1];
  const float* W1 = (const float*)d_in[2];
  const float* b1 = (const float*)d_in[3];
  const float* W2 = (const float*)d_in[4];
  const float* b2 = (const float*)d_in[5];
  const float* qw = (const float*)d_in[6];
  const float* qb = (const float*)d_in[7];
  const float* W3 = (const float*)d_in[8];
  const float* b3 = (const float*)d_in[9];
  const int* seq = (const int*)d_in[10];
  const int B = in_sizes[10];
  float* out = (float*)d_out;

  char* ws = (char*)d_ws;
  size_t o1 = (((size_t)B * 4) + 255) & ~(size_t)255;  // after offsets
  int* offs = (int*)ws;
  unsigned short* w1b = (unsigned short*)(ws + o1);            // 32 KB
  unsigned short* w2b = (unsigned short*)(ws + o1 + 32768);    // 32 KB
  unsigned short* w3b = (unsigned short*)(ws + o1 + 65536);    // 64 KB

  int nblk = B < 256 ? B : 256;  // 1 block/CU (LDS-limited); 32 sessions/block

  hipLaunchKernelGGL(prep_kernel, dim3(129), dim3(256), 0, stream,
                     seq, offs, B, W1, W2, W3, w1b, w2b, w3b);
  hipLaunchKernelGGL(session_kernel, dim3(nblk), dim3(256), 0, stream,
                     intra, inter, w1b, b1, w2b, b2, qw, qb, w3b, b3, seq, offs, out, B);
}